// Round 9
// baseline (3982.534 us; speedup 1.0000x reference)
//
#include <hip/hip_runtime.h>
#include <hip/hip_cooperative_groups.h>
#include <hip/hip_fp16.h>
#include <math.h>

namespace cg = cooperative_groups;

#define BB 4
#define HH 480
#define WW 640
#define HW (HH * WW)
#define PP (BB * HW)   // 1,228,800 pixels

#define NBLK 960       // persistent grid: 960 blocks x 256 thr, 5 px/thread
#define PXT 5          // 960*256*5 == PP; HW/1280 = 240 -> block never straddles images

// Bilinear corner load with zero padding (precompute only)
__device__ __forceinline__ float ldz(const float* __restrict__ img, int y, int x) {
    bool v = ((unsigned)y < (unsigned)HH) & ((unsigned)x < (unsigned)WW);
    int off = v ? (y * WW + x) : 0;
    float val = img[off];
    return v ? val : 0.0f;
}

// Axis mapping for zero-padded bilinear on a clamped 2x2 square:
// contribution along this axis == s * [(1-t)*I[c0] + t*I[c0+1]], c0 in [0, H-2].
__device__ __forceinline__ void axis_map(int y0, float wy, int H,
                                         int& c0, float& t, float& s) {
    if (y0 >= 0 && y0 <= H - 2)      { c0 = y0;    t = wy;   s = 1.0f; }
    else if (y0 == -1)               { c0 = 0;     t = 0.0f; s = wy; }
    else if (y0 == H - 1)            { c0 = H - 2; t = 1.0f; s = 1.0f - wy; }
    else                             { c0 = 0;     t = 0.0f; s = 0.0f; }
}

// fast tanh: 1 - 2/(exp(2x)+1)
__device__ __forceinline__ float tanh_fast(float x) {
    return 1.0f - 2.0f / (__expf(2.0f * x) + 1.0f);
}

// ---------------------------------------------------------------------------
// Kernel 0: transpose weights [c=24][ci=8][k=9] -> wT[k=9][ci=8][c=24]
// ---------------------------------------------------------------------------
__global__ void transpose_w_kernel(const float* __restrict__ w_oa, float* __restrict__ wT) {
    for (int i = threadIdx.x; i < 1728; i += 256) {
        const int k = i / 192;
        const int r = i - k * 192;
        const int ci = r / 24;
        const int c = r - ci * 24;
        wT[i] = w_oa[c * 72 + ci * 9 + k];
    }
}

// ---------------------------------------------------------------------------
// Kernel 1: per-pixel precompute (round-8 math, linear base19 packing).
// Per tap j (8 B): u32{ (y0c*W+x0c) << 13 | aff13 }, u32{ half2(ty,tx) }
// aff13 includes the zero-pad scale sy*sx. affC = center weight * 8192.
// ---------------------------------------------------------------------------
__global__ __launch_bounds__(256) void precompute_kernel(
    const float* __restrict__ guidance,
    const float* __restrict__ confidence,
    const float* __restrict__ wT,
    const float* __restrict__ b_oa,
    const float* __restrict__ aff_scale,
    uint4* __restrict__ PK4,
    float* __restrict__ affC)
{
    const int p = blockIdx.x * 256 + threadIdx.x;
    const int b = p / HW;
    const int rem = p - b * HW;
    const int y = rem / WW;
    const int x = rem - y * WW;

    float acc[24];
    #pragma unroll
    for (int c = 0; c < 24; ++c) acc[c] = b_oa[c];   // uniform -> s_load

    const float* gb = guidance + (size_t)b * 8 * HW;

    #pragma unroll 1
    for (int kidx = 0; kidx < 9; ++kidx) {
        const int yy = y + kidx / 3 - 1;
        const int xx = x + kidx % 3 - 1;
        const bool valid = ((unsigned)yy < (unsigned)HH) & ((unsigned)xx < (unsigned)WW);
        const int base = valid ? (yy * WW + xx) : 0;
        float g[8];
        #pragma unroll
        for (int ci = 0; ci < 8; ++ci) {
            float v = gb[ci * HW + base];
            g[ci] = valid ? v : 0.0f;
        }
        const float* wk = wT + kidx * 192;   // uniform address -> scalar loads
        #pragma unroll
        for (int ci = 0; ci < 8; ++ci) {
            const float gv = g[ci];
            #pragma unroll
            for (int c = 0; c < 24; ++c)
                acc[c] = fmaf(gv, wk[ci * 24 + c], acc[c]);
        }
    }

    // --- affinity head ---
    const float inv_scale = 1.0f / (aff_scale[0] + 1e-8f);
    const float* cb = confidence + (size_t)b * HW;
    const float fy = (float)y, fx = (float)x;

    float affv[8];
    #pragma unroll
    for (int j = 0; j < 8; ++j) {
        const float oy = acc[j], ox = acc[8 + j];
        const float a = tanh_fast(acc[16 + j]) * inv_scale;
        const float ysj = fy + oy, xsj = fx + ox;
        const float y0f = floorf(ysj), x0f = floorf(xsj);
        const float wy = ysj - y0f, wx = xsj - x0f;
        const int y0 = (int)y0f, x0 = (int)x0f;
        const float v00 = ldz(cb, y0, x0),     v01 = ldz(cb, y0, x0 + 1);
        const float v10 = ldz(cb, y0 + 1, x0), v11 = ldz(cb, y0 + 1, x0 + 1);
        const float conf = v00 * (1.0f - wy) * (1.0f - wx) + v01 * (1.0f - wy) * wx
                         + v10 * wy * (1.0f - wx)          + v11 * wy * wx;
        affv[j] = a * conf;
    }

    float s = 1e-4f;
    #pragma unroll
    for (int j = 0; j < 8; ++j) s += fabsf(affv[j]);
    s = fmaxf(s, 1.0f);
    const float inv_s = 1.0f / s;
    float sum = 0.0f;
    #pragma unroll
    for (int j = 0; j < 8; ++j) { affv[j] *= inv_s; sum += affv[j]; }
    const float aref = 1.0f - sum;

    float m = aref;
    #pragma unroll
    for (int j = 0; j < 8; ++j) m = fmaxf(m, affv[j]);
    float e[8];
    float denom = 0.0f;
    #pragma unroll
    for (int j = 0; j < 8; ++j) { e[j] = __expf(affv[j] - m); denom += e[j]; }
    const float ec = __expf(aref - m);
    denom += ec;
    const float invden = 1.0f / denom;

    affC[p] = ec * invden * 8192.0f;   // pre-scaled center weight

    unsigned ba[8], tt[8];
    #pragma unroll
    for (int j = 0; j < 8; ++j) {
        const int t9 = (j < 4) ? j : j + 1;          // 9-tap index (skip center 4)
        const float khv = (float)(t9 / 3 - 1);
        const float kwv = (float)(t9 % 3 - 1);
        const float ys = (fy + khv) + acc[j];
        const float xs = (fx + kwv) + acc[8 + j];
        const float y0f = floorf(ys), x0f = floorf(xs);
        const float wy = ys - y0f, wx = xs - x0f;
        int y0c, x0c; float ty, tx, sy, sx;
        axis_map((int)y0f, wy, HH, y0c, ty, sy);
        axis_map((int)x0f, wx, WW, x0c, tx, sx);

        const float aeff = (e[j] * invden) * sy * sx;           // in [0,1)
        unsigned aq = __float2uint_rn(aeff * 8192.0f);
        aq = aq > 8191u ? 8191u : aq;
        ba[j] = ((unsigned)(y0c * WW + x0c) << 13) | aq;        // base19 | aff13
        __half2 h2 = __floats2half2_rn(ty, tx);                 // low = ty, high = tx
        tt[j] = __builtin_bit_cast(unsigned, h2);
    }
    PK4[4 * p + 0] = make_uint4(ba[0], tt[0], ba[1], tt[1]);
    PK4[4 * p + 1] = make_uint4(ba[2], tt[2], ba[3], tt[3]);
    PK4[4 * p + 2] = make_uint4(ba[4], tt[4], ba[5], tt[5]);
    PK4[4 * p + 3] = make_uint4(ba[6], tt[6], ba[7], tt[7]);
}

// ---------------------------------------------------------------------------
// Kernel 2a: persistent cooperative propagation — all 18 iterations in one
// dispatch. Params live in registers for the whole kernel; per iteration only
// cached feature gathers + one coalesced store + grid sync.
// ---------------------------------------------------------------------------
__global__ __launch_bounds__(256, 4) void prop_persist_kernel(
    const float* __restrict__ feat_init,
    float* __restrict__ bufA,
    float* __restrict__ out,
    const uint4* __restrict__ PK4,
    const float* __restrict__ affC)
{
    const int tid = threadIdx.x;
    const int p0 = blockIdx.x * (256 * PXT) + tid;
    const int bofs = (p0 / HW) * HW;           // uniform per block (1280 | HW)

    // ---- load all per-pixel params into registers (persist 18 iters) ----
    uint4 q[PXT][4];
    float ac[PXT];
    #pragma unroll
    for (int k = 0; k < PXT; ++k) {
        const int p = p0 + k * 256;
        q[k][0] = PK4[4 * p + 0];
        q[k][1] = PK4[4 * p + 1];
        q[k][2] = PK4[4 * p + 2];
        q[k][3] = PK4[4 * p + 3];
        ac[k] = affC[p];
    }

    cg::grid_group grid = cg::this_grid();

    const float* src = feat_init;
    #pragma unroll 1
    for (int it = 0; it < 18; ++it) {
        float* dst = (it & 1) ? out : bufA;
        const float* fb = src + bofs;

        #pragma unroll
        for (int k = 0; k < PXT; ++k) {
            const int p = p0 + k * 256;
            float acc = ac[k] * src[p];        // center tap

            auto tap = [&](unsigned bav, unsigned tw) {
                const float af = (float)(bav & 8191u);
                const float* g = fb + (bav >> 13);
                const float2 t2 = *reinterpret_cast<const float2*>(g);
                const float2 b2 = *reinterpret_cast<const float2*>(g + WW);
                const float2 t = __half22float2(__builtin_bit_cast(__half2, tw));
                const float top = fmaf(t.y, t2.y - t2.x, t2.x);
                const float bot = fmaf(t.y, b2.y - b2.x, b2.x);
                acc = fmaf(af, fmaf(t.x, bot - top, top), acc);
            };
            tap(q[k][0].x, q[k][0].y); tap(q[k][0].z, q[k][0].w);
            tap(q[k][1].x, q[k][1].y); tap(q[k][1].z, q[k][1].w);
            tap(q[k][2].x, q[k][2].y); tap(q[k][2].z, q[k][2].w);
            tap(q[k][3].x, q[k][3].y); tap(q[k][3].z, q[k][3].w);

            dst[p] = acc * (1.0f / 8192.0f);
        }

        if (it < 17) {
            __threadfence();    // device-scope: flush for cross-XCD readers
            grid.sync();
        }
        src = dst;
    }
}

// ---------------------------------------------------------------------------
// Kernel 2b: fallback single-step prop (round-6 proven path), used only if
// cooperative launch is unavailable.
// ---------------------------------------------------------------------------
__global__ __launch_bounds__(256) void prop_kernel(
    const float* __restrict__ src,
    float* __restrict__ dst,
    const uint4* __restrict__ PK4,
    const float* __restrict__ affC)
{
    const int p = blockIdx.x * 256 + threadIdx.x;
    const int b = p / HW;
    const float* fb = src + (size_t)b * HW;

    const uint4 q0 = PK4[4 * p + 0];
    const uint4 q1 = PK4[4 * p + 1];
    const uint4 q2 = PK4[4 * p + 2];
    const uint4 q3 = PK4[4 * p + 3];

    float acc = 0.0f;
    auto tap = [&](unsigned bav, unsigned tw) {
        const float af = (float)(bav & 8191u);
        const float* g = fb + (bav >> 13);
        const float2 t2 = *reinterpret_cast<const float2*>(g);
        const float2 b2 = *reinterpret_cast<const float2*>(g + WW);
        const float2 t = __half22float2(__builtin_bit_cast(__half2, tw));
        const float top = fmaf(t.y, t2.y - t2.x, t2.x);
        const float bot = fmaf(t.y, b2.y - b2.x, b2.x);
        acc = fmaf(af, fmaf(t.x, bot - top, top), acc);
    };
    tap(q0.x, q0.y); tap(q0.z, q0.w);
    tap(q1.x, q1.y); tap(q1.z, q1.w);
    tap(q2.x, q2.y); tap(q2.z, q2.w);
    tap(q3.x, q3.y); tap(q3.z, q3.w);

    dst[p] = fmaf(affC[p], src[p], acc) * (1.0f / 8192.0f);
}

extern "C" void kernel_launch(void* const* d_in, const int* in_sizes, int n_in,
                              void* d_out, int out_size, void* d_ws, size_t ws_size,
                              hipStream_t stream) {
    const float* feat_init  = (const float*)d_in[0];
    const float* guidance   = (const float*)d_in[1];
    const float* confidence = (const float*)d_in[2];
    const float* w_oa       = (const float*)d_in[3];
    const float* b_oa       = (const float*)d_in[4];
    const float* aff_scale  = (const float*)d_in[5];
    float* out = (float*)d_out;
    float* ws  = (float*)d_ws;

    // ws layout (floats): PK4[16P] | affC[P] | bufA[P]; wT aliases bufA
    const size_t need = (size_t)18 * PP * sizeof(float);
    if (ws_size < need) return;  // fail visibly rather than corrupt

    uint4* PK4  = reinterpret_cast<uint4*>(ws);
    float* affC = ws + (size_t)16 * PP;
    float* bufA = ws + (size_t)17 * PP;
    float* wT   = bufA;

    const int grid = PP / 256;
    transpose_w_kernel<<<1, 256, 0, stream>>>(w_oa, wT);
    precompute_kernel<<<grid, 256, 0, stream>>>(guidance, confidence, wT, b_oa,
                                                aff_scale, PK4, affC);

    // persistent cooperative prop (all 18 iters, result -> out since 17 is odd)
    const float* fi = feat_init;
    float* ba = bufA;
    float* op = out;
    const uint4* pk = PK4;
    const float* af = affC;
    void* kargs[] = { (void*)&fi, (void*)&ba, (void*)&op, (void*)&pk, (void*)&af };
    hipError_t e = hipLaunchCooperativeKernel(
        reinterpret_cast<void*>(prop_persist_kernel),
        dim3(NBLK), dim3(256), kargs, 0, stream);

    if (e != hipSuccess) {
        // deterministic fallback: 18 single-step launches (round-6 path)
        const float* srcp = feat_init;
        for (int i = 0; i < 18; ++i) {
            float* dstp = (i & 1) ? out : bufA;
            prop_kernel<<<grid, 256, 0, stream>>>(srcp, dstp, PK4, affC);
            srcp = dstp;
        }
    }
}

// Round 10
// 615.816 us; speedup vs baseline: 6.4671x; 6.4671x over previous
//
#include <hip/hip_runtime.h>
#include <hip/hip_fp16.h>
#include <math.h>

#define BB 4
#define HH 480
#define WW 640
#define HW (HH * WW)
#define PP (BB * HW)   // 1,228,800 pixels

#define PXT 5          // pixels per thread in prop
#define NBLK (PP / (256 * PXT))   // 960 blocks; 1280 px/block, HW % 1280 == 0

// Bilinear corner load with zero padding (precompute only)
__device__ __forceinline__ float ldz(const float* __restrict__ img, int y, int x) {
    bool v = ((unsigned)y < (unsigned)HH) & ((unsigned)x < (unsigned)WW);
    int off = v ? (y * WW + x) : 0;
    float val = img[off];
    return v ? val : 0.0f;
}

// Axis mapping for zero-padded bilinear on a clamped 2x2 square:
// contribution along this axis == s * [(1-t)*I[c0] + t*I[c0+1]], c0 in [0, H-2].
__device__ __forceinline__ void axis_map(int y0, float wy, int H,
                                         int& c0, float& t, float& s) {
    if (y0 >= 0 && y0 <= H - 2)      { c0 = y0;    t = wy;   s = 1.0f; }
    else if (y0 == -1)               { c0 = 0;     t = 0.0f; s = wy; }
    else if (y0 == H - 1)            { c0 = H - 2; t = 1.0f; s = 1.0f - wy; }
    else                             { c0 = 0;     t = 0.0f; s = 0.0f; }
}

// fast tanh: 1 - 2/(exp(2x)+1)
__device__ __forceinline__ float tanh_fast(float x) {
    return 1.0f - 2.0f / (__expf(2.0f * x) + 1.0f);
}

// ---------------------------------------------------------------------------
// Kernel 0: transpose weights [c=24][ci=8][k=9] -> wT[k=9][ci=8][c=24]
// ---------------------------------------------------------------------------
__global__ void transpose_w_kernel(const float* __restrict__ w_oa, float* __restrict__ wT) {
    for (int i = threadIdx.x; i < 1728; i += 256) {
        const int k = i / 192;
        const int r = i - k * 192;
        const int ci = r / 24;
        const int c = r - ci * 24;
        wT[i] = w_oa[c * 72 + ci * 9 + k];
    }
}

// ---------------------------------------------------------------------------
// Kernel 1: per-pixel precompute (unchanged from round 8 — 98-102 us proven).
// Per tap j (8 B): u32{ (y0c*W+x0c) << 13 | aff13 }, u32{ half2(ty,tx) }
// aff13 includes the zero-pad scale sy*sx. affC = center weight * 8192.
// ---------------------------------------------------------------------------
__global__ __launch_bounds__(256) void precompute_kernel(
    const float* __restrict__ guidance,
    const float* __restrict__ confidence,
    const float* __restrict__ wT,
    const float* __restrict__ b_oa,
    const float* __restrict__ aff_scale,
    uint4* __restrict__ PK4,
    float* __restrict__ affC)
{
    const int p = blockIdx.x * 256 + threadIdx.x;
    const int b = p / HW;
    const int rem = p - b * HW;
    const int y = rem / WW;
    const int x = rem - y * WW;

    float acc[24];
    #pragma unroll
    for (int c = 0; c < 24; ++c) acc[c] = b_oa[c];   // uniform -> s_load

    const float* gb = guidance + (size_t)b * 8 * HW;

    #pragma unroll 1
    for (int kidx = 0; kidx < 9; ++kidx) {
        const int yy = y + kidx / 3 - 1;
        const int xx = x + kidx % 3 - 1;
        const bool valid = ((unsigned)yy < (unsigned)HH) & ((unsigned)xx < (unsigned)WW);
        const int base = valid ? (yy * WW + xx) : 0;
        float g[8];
        #pragma unroll
        for (int ci = 0; ci < 8; ++ci) {
            float v = gb[ci * HW + base];
            g[ci] = valid ? v : 0.0f;
        }
        const float* wk = wT + kidx * 192;   // uniform address -> scalar loads
        #pragma unroll
        for (int ci = 0; ci < 8; ++ci) {
            const float gv = g[ci];
            #pragma unroll
            for (int c = 0; c < 24; ++c)
                acc[c] = fmaf(gv, wk[ci * 24 + c], acc[c]);
        }
    }

    // --- affinity head ---
    const float inv_scale = 1.0f / (aff_scale[0] + 1e-8f);
    const float* cb = confidence + (size_t)b * HW;
    const float fy = (float)y, fx = (float)x;

    float affv[8];
    #pragma unroll
    for (int j = 0; j < 8; ++j) {
        const float oy = acc[j], ox = acc[8 + j];
        const float a = tanh_fast(acc[16 + j]) * inv_scale;
        const float ysj = fy + oy, xsj = fx + ox;
        const float y0f = floorf(ysj), x0f = floorf(xsj);
        const float wy = ysj - y0f, wx = xsj - x0f;
        const int y0 = (int)y0f, x0 = (int)x0f;
        const float v00 = ldz(cb, y0, x0),     v01 = ldz(cb, y0, x0 + 1);
        const float v10 = ldz(cb, y0 + 1, x0), v11 = ldz(cb, y0 + 1, x0 + 1);
        const float conf = v00 * (1.0f - wy) * (1.0f - wx) + v01 * (1.0f - wy) * wx
                         + v10 * wy * (1.0f - wx)          + v11 * wy * wx;
        affv[j] = a * conf;
    }

    float s = 1e-4f;
    #pragma unroll
    for (int j = 0; j < 8; ++j) s += fabsf(affv[j]);
    s = fmaxf(s, 1.0f);
    const float inv_s = 1.0f / s;
    float sum = 0.0f;
    #pragma unroll
    for (int j = 0; j < 8; ++j) { affv[j] *= inv_s; sum += affv[j]; }
    const float aref = 1.0f - sum;

    float m = aref;
    #pragma unroll
    for (int j = 0; j < 8; ++j) m = fmaxf(m, affv[j]);
    float e[8];
    float denom = 0.0f;
    #pragma unroll
    for (int j = 0; j < 8; ++j) { e[j] = __expf(affv[j] - m); denom += e[j]; }
    const float ec = __expf(aref - m);
    denom += ec;
    const float invden = 1.0f / denom;

    affC[p] = ec * invden * 8192.0f;   // pre-scaled center weight

    unsigned ba[8], tt[8];
    #pragma unroll
    for (int j = 0; j < 8; ++j) {
        const int t9 = (j < 4) ? j : j + 1;          // 9-tap index (skip center 4)
        const float khv = (float)(t9 / 3 - 1);
        const float kwv = (float)(t9 % 3 - 1);
        const float ys = (fy + khv) + acc[j];
        const float xs = (fx + kwv) + acc[8 + j];
        const float y0f = floorf(ys), x0f = floorf(xs);
        const float wy = ys - y0f, wx = xs - x0f;
        int y0c, x0c; float ty, tx, sy, sx;
        axis_map((int)y0f, wy, HH, y0c, ty, sy);
        axis_map((int)x0f, wx, WW, x0c, tx, sx);

        const float aeff = (e[j] * invden) * sy * sx;           // in [0,1)
        unsigned aq = __float2uint_rn(aeff * 8192.0f);
        aq = aq > 8191u ? 8191u : aq;
        ba[j] = ((unsigned)(y0c * WW + x0c) << 13) | aq;        // base19 | aff13
        __half2 h2 = __floats2half2_rn(ty, tx);                 // low = ty, high = tx
        tt[j] = __builtin_bit_cast(unsigned, h2);
    }
    PK4[4 * p + 0] = make_uint4(ba[0], tt[0], ba[1], tt[1]);
    PK4[4 * p + 1] = make_uint4(ba[2], tt[2], ba[3], tt[3]);
    PK4[4 * p + 2] = make_uint4(ba[4], tt[4], ba[5], tt[5]);
    PK4[4 * p + 3] = make_uint4(ba[6], tt[6], ba[7], tt[7]);
}

// ---------------------------------------------------------------------------
// Kernel 2: one propagation step, 5 px/thread, 960 blocks (was 4800).
// Theory: per-dispatch cost at 4800 blocks was dominated by the block
// dispatch/ramp floor (~25 us invariant across all per-thread optimizations);
// the R9 persist kernel's non-sync residual showed the same math runs at
// ~10.6 us/iter at 960 blocks. Full unroll over the 5 px lets the compiler
// hoist VMEM issues for ILP at the reduced occupancy.
// ---------------------------------------------------------------------------
__global__ __launch_bounds__(256) void prop_kernel(
    const float* __restrict__ src,
    float* __restrict__ dst,
    const uint4* __restrict__ PK4,
    const float* __restrict__ affC)
{
    const int tid = threadIdx.x;
    const int p0 = blockIdx.x * (256 * PXT) + tid;
    const float* fb = src + (p0 / HW) * HW;    // uniform per block (1280 | HW)

    #pragma unroll
    for (int k = 0; k < PXT; ++k) {
        const int p = p0 + k * 256;
        const uint4 q0 = PK4[4 * p + 0];
        const uint4 q1 = PK4[4 * p + 1];
        const uint4 q2 = PK4[4 * p + 2];
        const uint4 q3 = PK4[4 * p + 3];

        float acc = affC[p] * src[p];   // center tap

        auto tap = [&](unsigned bav, unsigned tw) {
            const float af = (float)(bav & 8191u);
            const float* g = fb + (bav >> 13);
            const float2 t2 = *reinterpret_cast<const float2*>(g);
            const float2 b2 = *reinterpret_cast<const float2*>(g + WW);
            const float2 t = __half22float2(__builtin_bit_cast(__half2, tw)); // (ty,tx)
            const float top = fmaf(t.y, t2.y - t2.x, t2.x);
            const float bot = fmaf(t.y, b2.y - b2.x, b2.x);
            acc = fmaf(af, fmaf(t.x, bot - top, top), acc);
        };
        tap(q0.x, q0.y); tap(q0.z, q0.w);
        tap(q1.x, q1.y); tap(q1.z, q1.w);
        tap(q2.x, q2.y); tap(q2.z, q2.w);
        tap(q3.x, q3.y); tap(q3.z, q3.w);

        dst[p] = acc * (1.0f / 8192.0f);
    }
}

extern "C" void kernel_launch(void* const* d_in, const int* in_sizes, int n_in,
                              void* d_out, int out_size, void* d_ws, size_t ws_size,
                              hipStream_t stream) {
    const float* feat_init  = (const float*)d_in[0];
    const float* guidance   = (const float*)d_in[1];
    const float* confidence = (const float*)d_in[2];
    const float* w_oa       = (const float*)d_in[3];
    const float* b_oa       = (const float*)d_in[4];
    const float* aff_scale  = (const float*)d_in[5];
    float* out = (float*)d_out;
    float* ws  = (float*)d_ws;

    // ws layout (floats): PK4[16P] | affC[P] | bufA[P]; wT aliases bufA
    const size_t need = (size_t)18 * PP * sizeof(float);
    if (ws_size < need) return;  // fail visibly rather than corrupt

    uint4* PK4  = reinterpret_cast<uint4*>(ws);
    float* affC = ws + (size_t)16 * PP;
    float* bufA = ws + (size_t)17 * PP;
    float* wT   = bufA;

    transpose_w_kernel<<<1, 256, 0, stream>>>(w_oa, wT);
    precompute_kernel<<<PP / 256, 256, 0, stream>>>(guidance, confidence, wT, b_oa,
                                                    aff_scale, PK4, affC);

    // ping-pong: even iters -> bufA, odd iters -> d_out (iter 17 -> d_out)
    const float* srcp = feat_init;
    for (int i = 0; i < 18; ++i) {
        float* dstp = (i & 1) ? out : bufA;
        prop_kernel<<<NBLK, 256, 0, stream>>>(srcp, dstp, PK4, affC);
        srcp = dstp;
    }
}

// Round 12
// 588.408 us; speedup vs baseline: 6.7683x; 1.0466x over previous
//
#include <hip/hip_runtime.h>
#include <hip/hip_fp16.h>
#include <math.h>

#define BB 4
#define HH 480
#define WW 640
#define HW (HH * WW)
#define PP (BB * HW)   // 1,228,800 pixels

#define PROP_NBLK (PP / 256)          // 4800, %8==0
#define PRE_NBLK  (PP / 1024)         // 1200, %8==0 (4 px/thread)

typedef unsigned u32x4 __attribute__((ext_vector_type(4)));  // nontemporal-compatible

// Axis mapping for zero-padded bilinear on a clamped 2x2 square:
// contribution along this axis == s * [(1-t)*I[c0] + t*I[c0+1]], c0 in [0, H-2].
__device__ __forceinline__ void axis_map(int y0, float wy, int H,
                                         int& c0, float& t, float& s) {
    if (y0 >= 0 && y0 <= H - 2)      { c0 = y0;    t = wy;   s = 1.0f; }
    else if (y0 == -1)               { c0 = 0;     t = 0.0f; s = wy; }
    else if (y0 == H - 1)            { c0 = H - 2; t = 1.0f; s = 1.0f - wy; }
    else                             { c0 = 0;     t = 0.0f; s = 0.0f; }
}

__device__ __forceinline__ float tanh_fast(float x) {
    return 1.0f - 2.0f / (__expf(2.0f * x) + 1.0f);
}

// zero-padded scalar load from a row-offset form
__device__ __forceinline__ float ldz2(const float* __restrict__ img, int rowoff,
                                      int xx, bool v) {
    const int xc = v ? xx : 0;
    const float val = img[rowoff + xc];
    return v ? val : 0.0f;
}

// ---------------------------------------------------------------------------
// Kernel 0: transpose weights [c=24][ci=8][k=9] -> wT[k=9][ci=8][c=24]
// ---------------------------------------------------------------------------
__global__ void transpose_w_kernel(const float* __restrict__ w_oa, float* __restrict__ wT) {
    for (int i = threadIdx.x; i < 1728; i += 256) {
        const int k = i / 192;
        const int r = i - k * 192;
        const int ci = r / 24;
        const int c = r - ci * 24;
        wT[i] = w_oa[c * 72 + ci * 9 + k];
    }
}

// ---------------------------------------------------------------------------
// Kernel 1: precompute, 4 consecutive px/thread + XCD-chunked swizzle.
// Conv accumulation order identical to round-6/8 kernel (bit-identical).
// Outputs: 4 SoA u32x4 streams PKa..PKd (taps {0,1},{2,3},{4,5},{6,7};
// each tap 8 B: u32{ base19<<13 | aff13 }, u32{ half2(ty,tx) }), affC f32.
// ---------------------------------------------------------------------------
__global__ __launch_bounds__(256) void precompute_kernel(
    const float* __restrict__ guidance,
    const float* __restrict__ confidence,
    const float* __restrict__ wT,
    const float* __restrict__ b_oa,
    const float* __restrict__ aff_scale,
    u32x4* __restrict__ PKa, u32x4* __restrict__ PKb,
    u32x4* __restrict__ PKc, u32x4* __restrict__ PKd,
    float* __restrict__ affC)
{
    // XCD-chunked bijective swizzle (1200 % 8 == 0)
    const int bid = (blockIdx.x & 7) * (PRE_NBLK / 8) + (blockIdx.x >> 3);
    const int p0 = bid * 1024 + (threadIdx.x << 2);   // quad start; WW%4==0 -> same row
    const int b = p0 / HW;
    const int rem = p0 - b * HW;
    const int y = rem / WW;
    const int x0 = rem - y * WW;

    const float* gb = guidance + (size_t)b * 8 * HW;

    float acc[4][24];
    #pragma unroll
    for (int q = 0; q < 4; ++q)
        #pragma unroll
        for (int c = 0; c < 24; ++c) acc[q][c] = b_oa[c];

    // column validity/indices for the 6-wide shared halo
    bool vc[6]; int xc[6];
    #pragma unroll
    for (int cx = 0; cx < 6; ++cx) {
        const int xx = x0 - 1 + cx;
        vc[cx] = ((unsigned)xx < (unsigned)WW);
        xc[cx] = vc[cx] ? xx : 0;
    }

    #pragma unroll 1
    for (int ky = 0; ky < 3; ++ky) {
        const int yy = y + ky - 1;
        const bool vrow = ((unsigned)yy < (unsigned)HH);
        const int rowoff = vrow ? yy * WW : 0;

        float g[8][6];
        #pragma unroll
        for (int ci = 0; ci < 8; ++ci)
            #pragma unroll
            for (int cx = 0; cx < 6; ++cx) {
                const float v = gb[ci * HW + rowoff + xc[cx]];
                g[ci][cx] = (vrow & vc[cx]) ? v : 0.0f;
            }

        #pragma unroll
        for (int kx = 0; kx < 3; ++kx) {
            const float* wk = wT + (ky * 3 + kx) * 192;   // uniform -> s_load
            #pragma unroll
            for (int ci = 0; ci < 8; ++ci) {
                #pragma unroll
                for (int c = 0; c < 24; ++c) {
                    const float w = wk[ci * 24 + c];
                    acc[0][c] = fmaf(g[ci][kx + 0], w, acc[0][c]);
                    acc[1][c] = fmaf(g[ci][kx + 1], w, acc[1][c]);
                    acc[2][c] = fmaf(g[ci][kx + 2], w, acc[2][c]);
                    acc[3][c] = fmaf(g[ci][kx + 3], w, acc[3][c]);
                }
            }
        }
    }

    // --- affinity head, per pixel (fully unrolled: static acc indexing) ---
    const float inv_scale = 1.0f / (aff_scale[0] + 1e-8f);
    const float* cb = confidence + (size_t)b * HW;
    float af4[4];
    u32x4 oa[4], ob[4], oc[4], od[4];

    #pragma unroll
    for (int q = 0; q < 4; ++q) {
        const int x = x0 + q;
        const float fy = (float)y, fx = (float)x;

        float affv[8];
        #pragma unroll
        for (int j = 0; j < 8; ++j) {
            const float oy = acc[q][j], ox = acc[q][8 + j];
            const float a = tanh_fast(acc[q][16 + j]) * inv_scale;
            const float ysj = fy + oy, xsj = fx + ox;
            const float y0f = floorf(ysj), x0f = floorf(xsj);
            const float wy = ysj - y0f, wx = xsj - x0f;
            const int y0 = (int)y0f, x0i = (int)x0f;
            const bool vy0 = ((unsigned)y0 < (unsigned)HH);
            const bool vy1 = ((unsigned)(y0 + 1) < (unsigned)HH);
            const bool vx0 = ((unsigned)x0i < (unsigned)WW);
            const bool vx1 = ((unsigned)(x0i + 1) < (unsigned)WW);
            const int r0 = vy0 ? y0 * WW : 0;
            const int r1 = vy1 ? (y0 + 1) * WW : 0;
            const float v00 = ldz2(cb, r0, x0i, vy0 & vx0);
            const float v01 = ldz2(cb, r0, x0i + 1, vy0 & vx1);
            const float v10 = ldz2(cb, r1, x0i, vy1 & vx0);
            const float v11 = ldz2(cb, r1, x0i + 1, vy1 & vx1);
            const float conf = v00 * (1.0f - wy) * (1.0f - wx) + v01 * (1.0f - wy) * wx
                             + v10 * wy * (1.0f - wx)          + v11 * wy * wx;
            affv[j] = a * conf;
        }

        float s = 1e-4f;
        #pragma unroll
        for (int j = 0; j < 8; ++j) s += fabsf(affv[j]);
        s = fmaxf(s, 1.0f);
        const float inv_s = 1.0f / s;
        float sum = 0.0f;
        #pragma unroll
        for (int j = 0; j < 8; ++j) { affv[j] *= inv_s; sum += affv[j]; }
        const float aref = 1.0f - sum;

        float m = aref;
        #pragma unroll
        for (int j = 0; j < 8; ++j) m = fmaxf(m, affv[j]);
        float e[8];
        float denom = 0.0f;
        #pragma unroll
        for (int j = 0; j < 8; ++j) { e[j] = __expf(affv[j] - m); denom += e[j]; }
        const float ec = __expf(aref - m);
        denom += ec;
        const float invden = 1.0f / denom;

        af4[q] = ec * invden * 8192.0f;

        unsigned ba[8], tt[8];
        #pragma unroll
        for (int j = 0; j < 8; ++j) {
            const int t9 = (j < 4) ? j : j + 1;
            const float khv = (float)(t9 / 3 - 1);
            const float kwv = (float)(t9 % 3 - 1);
            const float ys = (fy + khv) + acc[q][j];
            const float xs = (fx + kwv) + acc[q][8 + j];
            const float y0f = floorf(ys), x0f = floorf(xs);
            const float wy = ys - y0f, wx = xs - x0f;
            int y0c, x0c; float ty, tx, sy, sx;
            axis_map((int)y0f, wy, HH, y0c, ty, sy);
            axis_map((int)x0f, wx, WW, x0c, tx, sx);

            const float aeff = (e[j] * invden) * sy * sx;
            unsigned aq = __float2uint_rn(aeff * 8192.0f);
            aq = aq > 8191u ? 8191u : aq;
            ba[j] = ((unsigned)(y0c * WW + x0c) << 13) | aq;
            __half2 h2 = __floats2half2_rn(ty, tx);
            tt[j] = __builtin_bit_cast(unsigned, h2);
        }
        oa[q] = (u32x4){ba[0], tt[0], ba[1], tt[1]};
        ob[q] = (u32x4){ba[2], tt[2], ba[3], tt[3]};
        oc[q] = (u32x4){ba[4], tt[4], ba[5], tt[5]};
        od[q] = (u32x4){ba[6], tt[6], ba[7], tt[7]};
    }

    #pragma unroll
    for (int q = 0; q < 4; ++q) {
        PKa[p0 + q] = oa[q];
        PKb[p0 + q] = ob[q];
        PKc[p0 + q] = oc[q];
        PKd[p0 + q] = od[q];
    }
    *reinterpret_cast<float4*>(&affC[p0]) = make_float4(af4[0], af4[1], af4[2], af4[3]);
}

// ---------------------------------------------------------------------------
// Kernel 2: one propagation step. 4800 blocks, 1 px/thread (best-known),
// + XCD-chunked swizzle (src slice per XCD = 614 KB -> L2-resident)
// + nontemporal loads on the use-once param streams (don't thrash L2).
// ---------------------------------------------------------------------------
__global__ __launch_bounds__(256) void prop_kernel(
    const float* __restrict__ src,
    float* __restrict__ dst,
    const u32x4* __restrict__ PKa, const u32x4* __restrict__ PKb,
    const u32x4* __restrict__ PKc, const u32x4* __restrict__ PKd,
    const float* __restrict__ affC)
{
    const int bid = (blockIdx.x & 7) * (PROP_NBLK / 8) + (blockIdx.x >> 3);
    const int p = bid * 256 + threadIdx.x;
    const float* fb = src + (p / HW) * HW;   // uniform per block (HW % 256 == 0)

    const u32x4 qa = __builtin_nontemporal_load(&PKa[p]);
    const u32x4 qb = __builtin_nontemporal_load(&PKb[p]);
    const u32x4 qc = __builtin_nontemporal_load(&PKc[p]);
    const u32x4 qd = __builtin_nontemporal_load(&PKd[p]);
    const float ac = __builtin_nontemporal_load(&affC[p]);

    float acc = ac * src[p];   // center tap

    auto tap = [&](unsigned bav, unsigned tw) {
        const float af = (float)(bav & 8191u);
        const float* g = fb + (bav >> 13);
        const float2 t2 = *reinterpret_cast<const float2*>(g);
        const float2 b2 = *reinterpret_cast<const float2*>(g + WW);
        const float2 t = __half22float2(__builtin_bit_cast(__half2, tw)); // (ty,tx)
        const float top = fmaf(t.y, t2.y - t2.x, t2.x);
        const float bot = fmaf(t.y, b2.y - b2.x, b2.x);
        acc = fmaf(af, fmaf(t.x, bot - top, top), acc);
    };
    tap(qa.x, qa.y); tap(qa.z, qa.w);
    tap(qb.x, qb.y); tap(qb.z, qb.w);
    tap(qc.x, qc.y); tap(qc.z, qc.w);
    tap(qd.x, qd.y); tap(qd.z, qd.w);

    dst[p] = acc * (1.0f / 8192.0f);
}

extern "C" void kernel_launch(void* const* d_in, const int* in_sizes, int n_in,
                              void* d_out, int out_size, void* d_ws, size_t ws_size,
                              hipStream_t stream) {
    const float* feat_init  = (const float*)d_in[0];
    const float* guidance   = (const float*)d_in[1];
    const float* confidence = (const float*)d_in[2];
    const float* w_oa       = (const float*)d_in[3];
    const float* b_oa       = (const float*)d_in[4];
    const float* aff_scale  = (const float*)d_in[5];
    float* out = (float*)d_out;
    float* ws  = (float*)d_ws;

    // ws layout (floats): PKa[4P] PKb[4P] PKc[4P] PKd[4P] | affC[P] | bufA[P]
    // wT (1728 floats) aliases bufA (dead before prop iter 0 writes it).
    const size_t need = (size_t)18 * PP * sizeof(float);
    if (ws_size < need) return;  // fail visibly rather than corrupt

    u32x4* PKa  = reinterpret_cast<u32x4*>(ws);
    u32x4* PKb  = reinterpret_cast<u32x4*>(ws + (size_t)4 * PP);
    u32x4* PKc  = reinterpret_cast<u32x4*>(ws + (size_t)8 * PP);
    u32x4* PKd  = reinterpret_cast<u32x4*>(ws + (size_t)12 * PP);
    float* affC = ws + (size_t)16 * PP;
    float* bufA = ws + (size_t)17 * PP;
    float* wT   = bufA;

    transpose_w_kernel<<<1, 256, 0, stream>>>(w_oa, wT);
    precompute_kernel<<<PRE_NBLK, 256, 0, stream>>>(guidance, confidence, wT, b_oa,
                                                    aff_scale, PKa, PKb, PKc, PKd, affC);

    // ping-pong: even iters -> bufA, odd iters -> d_out (iter 17 -> d_out)
    const float* srcp = feat_init;
    for (int i = 0; i < 18; ++i) {
        float* dstp = (i & 1) ? out : bufA;
        prop_kernel<<<PROP_NBLK, 256, 0, stream>>>(srcp, dstp, PKa, PKb, PKc, PKd, affC);
        srcp = dstp;
    }
}

// Round 13
// 542.423 us; speedup vs baseline: 7.3421x; 1.0848x over previous
//
#include <hip/hip_runtime.h>
#include <hip/hip_fp16.h>
#include <math.h>

#define BB 4
#define HH 480
#define WW 640
#define HW (HH * WW)
#define PP (BB * HW)   // 1,228,800 pixels

#define PROP_NBLK (PP / 256)          // 4800, %8==0

typedef unsigned u32x4 __attribute__((ext_vector_type(4)));  // nontemporal-compatible

// Bilinear corner load with zero padding (precompute only)
__device__ __forceinline__ float ldz(const float* __restrict__ img, int y, int x) {
    bool v = ((unsigned)y < (unsigned)HH) & ((unsigned)x < (unsigned)WW);
    int off = v ? (y * WW + x) : 0;
    float val = img[off];
    return v ? val : 0.0f;
}

// Axis mapping for zero-padded bilinear on a clamped 2x2 square:
// contribution along this axis == s * [(1-t)*I[c0] + t*I[c0+1]], c0 in [0, H-2].
__device__ __forceinline__ void axis_map(int y0, float wy, int H,
                                         int& c0, float& t, float& s) {
    if (y0 >= 0 && y0 <= H - 2)      { c0 = y0;    t = wy;   s = 1.0f; }
    else if (y0 == -1)               { c0 = 0;     t = 0.0f; s = wy; }
    else if (y0 == H - 1)            { c0 = H - 2; t = 1.0f; s = 1.0f - wy; }
    else                             { c0 = 0;     t = 0.0f; s = 0.0f; }
}

__device__ __forceinline__ float tanh_fast(float x) {
    return 1.0f - 2.0f / (__expf(2.0f * x) + 1.0f);
}

// ---------------------------------------------------------------------------
// Kernel 0: transpose weights [c=24][ci=8][k=9] -> wT[k=9][ci=8][c=24]
// ---------------------------------------------------------------------------
__global__ void transpose_w_kernel(const float* __restrict__ w_oa, float* __restrict__ wT) {
    for (int i = threadIdx.x; i < 1728; i += 256) {
        const int k = i / 192;
        const int r = i - k * 192;
        const int ci = r / 24;
        const int c = r - ci * 24;
        wT[i] = w_oa[c * 72 + ci * 9 + k];
    }
}

// ---------------------------------------------------------------------------
// Kernel 1: per-pixel precompute — R8-proven structure (1 px/thread,
// #pragma unroll 1 kidx loop, VGPR ~60, 96-101 us measured), emitting the
// SoA streams PKa..PKd the swizzled prop consumes.
// Per tap j (8 B): u32{ (y0c*W+x0c) << 13 | aff13 }, u32{ half2(ty,tx) }
// aff13 includes the zero-pad scale sy*sx. affC = center weight * 8192.
// ---------------------------------------------------------------------------
__global__ __launch_bounds__(256) void precompute_kernel(
    const float* __restrict__ guidance,
    const float* __restrict__ confidence,
    const float* __restrict__ wT,
    const float* __restrict__ b_oa,
    const float* __restrict__ aff_scale,
    u32x4* __restrict__ PKa, u32x4* __restrict__ PKb,
    u32x4* __restrict__ PKc, u32x4* __restrict__ PKd,
    float* __restrict__ affC)
{
    const int p = blockIdx.x * 256 + threadIdx.x;
    const int b = p / HW;
    const int rem = p - b * HW;
    const int y = rem / WW;
    const int x = rem - y * WW;

    float acc[24];
    #pragma unroll
    for (int c = 0; c < 24; ++c) acc[c] = b_oa[c];   // uniform -> s_load

    const float* gb = guidance + (size_t)b * 8 * HW;

    #pragma unroll 1
    for (int kidx = 0; kidx < 9; ++kidx) {
        const int yy = y + kidx / 3 - 1;
        const int xx = x + kidx % 3 - 1;
        const bool valid = ((unsigned)yy < (unsigned)HH) & ((unsigned)xx < (unsigned)WW);
        const int base = valid ? (yy * WW + xx) : 0;
        float g[8];
        #pragma unroll
        for (int ci = 0; ci < 8; ++ci) {
            float v = gb[ci * HW + base];
            g[ci] = valid ? v : 0.0f;
        }
        const float* wk = wT + kidx * 192;   // uniform address -> scalar loads
        #pragma unroll
        for (int ci = 0; ci < 8; ++ci) {
            const float gv = g[ci];
            #pragma unroll
            for (int c = 0; c < 24; ++c)
                acc[c] = fmaf(gv, wk[ci * 24 + c], acc[c]);
        }
    }

    // --- affinity head ---
    const float inv_scale = 1.0f / (aff_scale[0] + 1e-8f);
    const float* cb = confidence + (size_t)b * HW;
    const float fy = (float)y, fx = (float)x;

    float affv[8];
    #pragma unroll
    for (int j = 0; j < 8; ++j) {
        const float oy = acc[j], ox = acc[8 + j];
        const float a = tanh_fast(acc[16 + j]) * inv_scale;
        const float ysj = fy + oy, xsj = fx + ox;
        const float y0f = floorf(ysj), x0f = floorf(xsj);
        const float wy = ysj - y0f, wx = xsj - x0f;
        const int y0 = (int)y0f, x0 = (int)x0f;
        const float v00 = ldz(cb, y0, x0),     v01 = ldz(cb, y0, x0 + 1);
        const float v10 = ldz(cb, y0 + 1, x0), v11 = ldz(cb, y0 + 1, x0 + 1);
        const float conf = v00 * (1.0f - wy) * (1.0f - wx) + v01 * (1.0f - wy) * wx
                         + v10 * wy * (1.0f - wx)          + v11 * wy * wx;
        affv[j] = a * conf;
    }

    float s = 1e-4f;
    #pragma unroll
    for (int j = 0; j < 8; ++j) s += fabsf(affv[j]);
    s = fmaxf(s, 1.0f);
    const float inv_s = 1.0f / s;
    float sum = 0.0f;
    #pragma unroll
    for (int j = 0; j < 8; ++j) { affv[j] *= inv_s; sum += affv[j]; }
    const float aref = 1.0f - sum;

    float m = aref;
    #pragma unroll
    for (int j = 0; j < 8; ++j) m = fmaxf(m, affv[j]);
    float e[8];
    float denom = 0.0f;
    #pragma unroll
    for (int j = 0; j < 8; ++j) { e[j] = __expf(affv[j] - m); denom += e[j]; }
    const float ec = __expf(aref - m);
    denom += ec;
    const float invden = 1.0f / denom;

    affC[p] = ec * invden * 8192.0f;   // pre-scaled center weight

    unsigned ba[8], tt[8];
    #pragma unroll
    for (int j = 0; j < 8; ++j) {
        const int t9 = (j < 4) ? j : j + 1;          // 9-tap index (skip center 4)
        const float khv = (float)(t9 / 3 - 1);
        const float kwv = (float)(t9 % 3 - 1);
        const float ys = (fy + khv) + acc[j];
        const float xs = (fx + kwv) + acc[8 + j];
        const float y0f = floorf(ys), x0f = floorf(xs);
        const float wy = ys - y0f, wx = xs - x0f;
        int y0c, x0c; float ty, tx, sy, sx;
        axis_map((int)y0f, wy, HH, y0c, ty, sy);
        axis_map((int)x0f, wx, WW, x0c, tx, sx);

        const float aeff = (e[j] * invden) * sy * sx;           // in [0,1)
        unsigned aq = __float2uint_rn(aeff * 8192.0f);
        aq = aq > 8191u ? 8191u : aq;
        ba[j] = ((unsigned)(y0c * WW + x0c) << 13) | aq;        // base19 | aff13
        __half2 h2 = __floats2half2_rn(ty, tx);                 // low = ty, high = tx
        tt[j] = __builtin_bit_cast(unsigned, h2);
    }
    PKa[p] = (u32x4){ba[0], tt[0], ba[1], tt[1]};
    PKb[p] = (u32x4){ba[2], tt[2], ba[3], tt[3]};
    PKc[p] = (u32x4){ba[4], tt[4], ba[5], tt[5]};
    PKd[p] = (u32x4){ba[6], tt[6], ba[7], tt[7]};
}

// ---------------------------------------------------------------------------
// Kernel 2: one propagation step — R12-proven (best measured, 24.4 us/iter).
// 4800 blocks, 1 px/thread, XCD-chunked swizzle (src slice per XCD L2-resident)
// + nontemporal loads on the use-once param streams.
// ---------------------------------------------------------------------------
__global__ __launch_bounds__(256) void prop_kernel(
    const float* __restrict__ src,
    float* __restrict__ dst,
    const u32x4* __restrict__ PKa, const u32x4* __restrict__ PKb,
    const u32x4* __restrict__ PKc, const u32x4* __restrict__ PKd,
    const float* __restrict__ affC)
{
    const int bid = (blockIdx.x & 7) * (PROP_NBLK / 8) + (blockIdx.x >> 3);
    const int p = bid * 256 + threadIdx.x;
    const float* fb = src + (p / HW) * HW;   // uniform per block (HW % 256 == 0)

    const u32x4 qa = __builtin_nontemporal_load(&PKa[p]);
    const u32x4 qb = __builtin_nontemporal_load(&PKb[p]);
    const u32x4 qc = __builtin_nontemporal_load(&PKc[p]);
    const u32x4 qd = __builtin_nontemporal_load(&PKd[p]);
    const float ac = __builtin_nontemporal_load(&affC[p]);

    float acc = ac * src[p];   // center tap

    auto tap = [&](unsigned bav, unsigned tw) {
        const float af = (float)(bav & 8191u);
        const float* g = fb + (bav >> 13);
        const float2 t2 = *reinterpret_cast<const float2*>(g);
        const float2 b2 = *reinterpret_cast<const float2*>(g + WW);
        const float2 t = __half22float2(__builtin_bit_cast(__half2, tw)); // (ty,tx)
        const float top = fmaf(t.y, t2.y - t2.x, t2.x);
        const float bot = fmaf(t.y, b2.y - b2.x, b2.x);
        acc = fmaf(af, fmaf(t.x, bot - top, top), acc);
    };
    tap(qa.x, qa.y); tap(qa.z, qa.w);
    tap(qb.x, qb.y); tap(qb.z, qb.w);
    tap(qc.x, qc.y); tap(qc.z, qc.w);
    tap(qd.x, qd.y); tap(qd.z, qd.w);

    dst[p] = acc * (1.0f / 8192.0f);
}

extern "C" void kernel_launch(void* const* d_in, const int* in_sizes, int n_in,
                              void* d_out, int out_size, void* d_ws, size_t ws_size,
                              hipStream_t stream) {
    const float* feat_init  = (const float*)d_in[0];
    const float* guidance   = (const float*)d_in[1];
    const float* confidence = (const float*)d_in[2];
    const float* w_oa       = (const float*)d_in[3];
    const float* b_oa       = (const float*)d_in[4];
    const float* aff_scale  = (const float*)d_in[5];
    float* out = (float*)d_out;
    float* ws  = (float*)d_ws;

    // ws layout (floats): PKa[4P] PKb[4P] PKc[4P] PKd[4P] | affC[P] | bufA[P]
    // wT (1728 floats) aliases bufA (dead before prop iter 0 writes it).
    const size_t need = (size_t)18 * PP * sizeof(float);
    if (ws_size < need) return;  // fail visibly rather than corrupt

    u32x4* PKa  = reinterpret_cast<u32x4*>(ws);
    u32x4* PKb  = reinterpret_cast<u32x4*>(ws + (size_t)4 * PP);
    u32x4* PKc  = reinterpret_cast<u32x4*>(ws + (size_t)8 * PP);
    u32x4* PKd  = reinterpret_cast<u32x4*>(ws + (size_t)12 * PP);
    float* affC = ws + (size_t)16 * PP;
    float* bufA = ws + (size_t)17 * PP;
    float* wT   = bufA;

    transpose_w_kernel<<<1, 256, 0, stream>>>(w_oa, wT);
    precompute_kernel<<<PP / 256, 256, 0, stream>>>(guidance, confidence, wT, b_oa,
                                                    aff_scale, PKa, PKb, PKc, PKd, affC);

    // ping-pong: even iters -> bufA, odd iters -> d_out (iter 17 -> d_out)
    const float* srcp = feat_init;
    for (int i = 0; i < 18; ++i) {
        float* dstp = (i & 1) ? out : bufA;
        prop_kernel<<<PROP_NBLK, 256, 0, stream>>>(srcp, dstp, PKa, PKb, PKc, PKd, affC);
        srcp = dstp;
    }
}

// Round 14
// 514.625 us; speedup vs baseline: 7.7387x; 1.0540x over previous
//
#include <hip/hip_runtime.h>
#include <hip/hip_fp16.h>
#include <math.h>

#define BB 4
#define HH 480
#define WW 640
#define HW (HH * WW)
#define PP (BB * HW)   // 1,228,800 pixels

#define PROP_NBLK (PP / 256)          // 4800, %8==0

typedef unsigned u32x4 __attribute__((ext_vector_type(4)));

// Bilinear corner load with zero padding (precompute only)
__device__ __forceinline__ float ldz(const float* __restrict__ img, int y, int x) {
    bool v = ((unsigned)y < (unsigned)HH) & ((unsigned)x < (unsigned)WW);
    int off = v ? (y * WW + x) : 0;
    float val = img[off];
    return v ? val : 0.0f;
}

// Axis mapping for zero-padded bilinear on a clamped 2x2 square:
// contribution along this axis == s * [(1-t)*I[c0] + t*I[c0+1]], c0 in [0, H-2].
__device__ __forceinline__ void axis_map(int y0, float wy, int H,
                                         int& c0, float& t, float& s) {
    if (y0 >= 0 && y0 <= H - 2)      { c0 = y0;    t = wy;   s = 1.0f; }
    else if (y0 == -1)               { c0 = 0;     t = 0.0f; s = wy; }
    else if (y0 == H - 1)            { c0 = H - 2; t = 1.0f; s = 1.0f - wy; }
    else                             { c0 = 0;     t = 0.0f; s = 0.0f; }
}

__device__ __forceinline__ float tanh_fast(float x) {
    return 1.0f - 2.0f / (__expf(2.0f * x) + 1.0f);
}

// ---------------------------------------------------------------------------
// Kernel 0: transpose weights [c=24][ci=8][k=9] -> wT[k=9][ci=8][c=24]
// ---------------------------------------------------------------------------
__global__ void transpose_w_kernel(const float* __restrict__ w_oa, float* __restrict__ wT) {
    for (int i = threadIdx.x; i < 1728; i += 256) {
        const int k = i / 192;
        const int r = i - k * 192;
        const int ci = r / 24;
        const int c = r - ci * 24;
        wT[i] = w_oa[c * 72 + ci * 9 + k];
    }
}

// ---------------------------------------------------------------------------
// Kernel 1: per-pixel precompute — R8/R13-proven structure (95-97 us, VGPR 60).
// Per tap j (8 B): u32{ (y0c*W+x0c) << 13 | aff13 }, u32{ half2(ty,tx) }
// aff13 includes the zero-pad scale sy*sx. affC = center weight * 8192.
// ---------------------------------------------------------------------------
__global__ __launch_bounds__(256) void precompute_kernel(
    const float* __restrict__ guidance,
    const float* __restrict__ confidence,
    const float* __restrict__ wT,
    const float* __restrict__ b_oa,
    const float* __restrict__ aff_scale,
    u32x4* __restrict__ PKa, u32x4* __restrict__ PKb,
    u32x4* __restrict__ PKc, u32x4* __restrict__ PKd,
    float* __restrict__ affC)
{
    const int p = blockIdx.x * 256 + threadIdx.x;
    const int b = p / HW;
    const int rem = p - b * HW;
    const int y = rem / WW;
    const int x = rem - y * WW;

    float acc[24];
    #pragma unroll
    for (int c = 0; c < 24; ++c) acc[c] = b_oa[c];   // uniform -> s_load

    const float* gb = guidance + (size_t)b * 8 * HW;

    #pragma unroll 1
    for (int kidx = 0; kidx < 9; ++kidx) {
        const int yy = y + kidx / 3 - 1;
        const int xx = x + kidx % 3 - 1;
        const bool valid = ((unsigned)yy < (unsigned)HH) & ((unsigned)xx < (unsigned)WW);
        const int base = valid ? (yy * WW + xx) : 0;
        float g[8];
        #pragma unroll
        for (int ci = 0; ci < 8; ++ci) {
            float v = gb[ci * HW + base];
            g[ci] = valid ? v : 0.0f;
        }
        const float* wk = wT + kidx * 192;   // uniform address -> scalar loads
        #pragma unroll
        for (int ci = 0; ci < 8; ++ci) {
            const float gv = g[ci];
            #pragma unroll
            for (int c = 0; c < 24; ++c)
                acc[c] = fmaf(gv, wk[ci * 24 + c], acc[c]);
        }
    }

    // --- affinity head ---
    const float inv_scale = 1.0f / (aff_scale[0] + 1e-8f);
    const float* cb = confidence + (size_t)b * HW;
    const float fy = (float)y, fx = (float)x;

    float affv[8];
    #pragma unroll
    for (int j = 0; j < 8; ++j) {
        const float oy = acc[j], ox = acc[8 + j];
        const float a = tanh_fast(acc[16 + j]) * inv_scale;
        const float ysj = fy + oy, xsj = fx + ox;
        const float y0f = floorf(ysj), x0f = floorf(xsj);
        const float wy = ysj - y0f, wx = xsj - x0f;
        const int y0 = (int)y0f, x0 = (int)x0f;
        const float v00 = ldz(cb, y0, x0),     v01 = ldz(cb, y0, x0 + 1);
        const float v10 = ldz(cb, y0 + 1, x0), v11 = ldz(cb, y0 + 1, x0 + 1);
        const float conf = v00 * (1.0f - wy) * (1.0f - wx) + v01 * (1.0f - wy) * wx
                         + v10 * wy * (1.0f - wx)          + v11 * wy * wx;
        affv[j] = a * conf;
    }

    float s = 1e-4f;
    #pragma unroll
    for (int j = 0; j < 8; ++j) s += fabsf(affv[j]);
    s = fmaxf(s, 1.0f);
    const float inv_s = 1.0f / s;
    float sum = 0.0f;
    #pragma unroll
    for (int j = 0; j < 8; ++j) { affv[j] *= inv_s; sum += affv[j]; }
    const float aref = 1.0f - sum;

    float m = aref;
    #pragma unroll
    for (int j = 0; j < 8; ++j) m = fmaxf(m, affv[j]);
    float e[8];
    float denom = 0.0f;
    #pragma unroll
    for (int j = 0; j < 8; ++j) { e[j] = __expf(affv[j] - m); denom += e[j]; }
    const float ec = __expf(aref - m);
    denom += ec;
    const float invden = 1.0f / denom;

    affC[p] = ec * invden * 8192.0f;   // pre-scaled center weight

    unsigned ba[8], tt[8];
    #pragma unroll
    for (int j = 0; j < 8; ++j) {
        const int t9 = (j < 4) ? j : j + 1;          // 9-tap index (skip center 4)
        const float khv = (float)(t9 / 3 - 1);
        const float kwv = (float)(t9 % 3 - 1);
        const float ys = (fy + khv) + acc[j];
        const float xs = (fx + kwv) + acc[8 + j];
        const float y0f = floorf(ys), x0f = floorf(xs);
        const float wy = ys - y0f, wx = xs - x0f;
        int y0c, x0c; float ty, tx, sy, sx;
        axis_map((int)y0f, wy, HH, y0c, ty, sy);
        axis_map((int)x0f, wx, WW, x0c, tx, sx);

        const float aeff = (e[j] * invden) * sy * sx;           // in [0,1)
        unsigned aq = __float2uint_rn(aeff * 8192.0f);
        aq = aq > 8191u ? 8191u : aq;
        ba[j] = ((unsigned)(y0c * WW + x0c) << 13) | aq;        // base19 | aff13
        __half2 h2 = __floats2half2_rn(ty, tx);                 // low = ty, high = tx
        tt[j] = __builtin_bit_cast(unsigned, h2);
    }
    PKa[p] = (u32x4){ba[0], tt[0], ba[1], tt[1]};
    PKb[p] = (u32x4){ba[2], tt[2], ba[3], tt[3]};
    PKc[p] = (u32x4){ba[4], tt[4], ba[5], tt[5]};
    PKd[p] = (u32x4){ba[6], tt[6], ba[7], tt[7]};
}

// ---------------------------------------------------------------------------
// Kernel 2: one propagation step. 4800 blocks, 1 px/thread, XCD-chunked
// swizzle. A/B vs R12/R13: nontemporal hints REMOVED — the param streams are
// re-read by all 18 launches and fit in the 256 MB Infinity Cache; nt forced
// HBM-rate re-streaming every iteration.
// ---------------------------------------------------------------------------
__global__ __launch_bounds__(256) void prop_kernel(
    const float* __restrict__ src,
    float* __restrict__ dst,
    const u32x4* __restrict__ PKa, const u32x4* __restrict__ PKb,
    const u32x4* __restrict__ PKc, const u32x4* __restrict__ PKd,
    const float* __restrict__ affC)
{
    const int bid = (blockIdx.x & 7) * (PROP_NBLK / 8) + (blockIdx.x >> 3);
    const int p = bid * 256 + threadIdx.x;
    const float* fb = src + (p / HW) * HW;   // uniform per block (HW % 256 == 0)

    const u32x4 qa = PKa[p];
    const u32x4 qb = PKb[p];
    const u32x4 qc = PKc[p];
    const u32x4 qd = PKd[p];
    const float ac = affC[p];

    float acc = ac * src[p];   // center tap

    auto tap = [&](unsigned bav, unsigned tw) {
        const float af = (float)(bav & 8191u);
        const float* g = fb + (bav >> 13);
        const float2 t2 = *reinterpret_cast<const float2*>(g);
        const float2 b2 = *reinterpret_cast<const float2*>(g + WW);
        const float2 t = __half22float2(__builtin_bit_cast(__half2, tw)); // (ty,tx)
        const float top = fmaf(t.y, t2.y - t2.x, t2.x);
        const float bot = fmaf(t.y, b2.y - b2.x, b2.x);
        acc = fmaf(af, fmaf(t.x, bot - top, top), acc);
    };
    tap(qa.x, qa.y); tap(qa.z, qa.w);
    tap(qb.x, qb.y); tap(qb.z, qb.w);
    tap(qc.x, qc.y); tap(qc.z, qc.w);
    tap(qd.x, qd.y); tap(qd.z, qd.w);

    dst[p] = acc * (1.0f / 8192.0f);
}

extern "C" void kernel_launch(void* const* d_in, const int* in_sizes, int n_in,
                              void* d_out, int out_size, void* d_ws, size_t ws_size,
                              hipStream_t stream) {
    const float* feat_init  = (const float*)d_in[0];
    const float* guidance   = (const float*)d_in[1];
    const float* confidence = (const float*)d_in[2];
    const float* w_oa       = (const float*)d_in[3];
    const float* b_oa       = (const float*)d_in[4];
    const float* aff_scale  = (const float*)d_in[5];
    float* out = (float*)d_out;
    float* ws  = (float*)d_ws;

    // ws layout (floats): PKa[4P] PKb[4P] PKc[4P] PKd[4P] | affC[P] | bufA[P]
    // wT (1728 floats) aliases bufA (dead before prop iter 0 writes it).
    const size_t need = (size_t)18 * PP * sizeof(float);
    if (ws_size < need) return;  // fail visibly rather than corrupt

    u32x4* PKa  = reinterpret_cast<u32x4*>(ws);
    u32x4* PKb  = reinterpret_cast<u32x4*>(ws + (size_t)4 * PP);
    u32x4* PKc  = reinterpret_cast<u32x4*>(ws + (size_t)8 * PP);
    u32x4* PKd  = reinterpret_cast<u32x4*>(ws + (size_t)12 * PP);
    float* affC = ws + (size_t)16 * PP;
    float* bufA = ws + (size_t)17 * PP;
    float* wT   = bufA;

    transpose_w_kernel<<<1, 256, 0, stream>>>(w_oa, wT);
    precompute_kernel<<<PP / 256, 256, 0, stream>>>(guidance, confidence, wT, b_oa,
                                                    aff_scale, PKa, PKb, PKc, PKd, affC);

    // ping-pong: even iters -> bufA, odd iters -> d_out (iter 17 -> d_out)
    const float* srcp = feat_init;
    for (int i = 0; i < 18; ++i) {
        float* dstp = (i & 1) ? out : bufA;
        prop_kernel<<<PROP_NBLK, 256, 0, stream>>>(srcp, dstp, PKa, PKb, PKc, PKd, affC);
        srcp = dstp;
    }
}

// Round 15
// 509.661 us; speedup vs baseline: 7.8141x; 1.0097x over previous
//
#include <hip/hip_runtime.h>
#include <hip/hip_fp16.h>
#include <math.h>

#define BB 4
#define HH 480
#define WW 640
#define HW (HH * WW)
#define PP (BB * HW)   // 1,228,800 pixels

#define PROP_NBLK (PP / 256)          // 4800, %8==0

typedef unsigned u32x4 __attribute__((ext_vector_type(4)));
typedef float f32x2 __attribute__((ext_vector_type(2)));

// Bilinear corner load with zero padding (precompute only)
__device__ __forceinline__ float ldz(const float* __restrict__ img, int y, int x) {
    bool v = ((unsigned)y < (unsigned)HH) & ((unsigned)x < (unsigned)WW);
    int off = v ? (y * WW + x) : 0;
    float val = img[off];
    return v ? val : 0.0f;
}

// Axis mapping for zero-padded bilinear on a clamped 2x2 square:
// contribution along this axis == s * [(1-t)*I[c0] + t*I[c0+1]], c0 in [0, H-2].
__device__ __forceinline__ void axis_map(int y0, float wy, int H,
                                         int& c0, float& t, float& s) {
    if (y0 >= 0 && y0 <= H - 2)      { c0 = y0;    t = wy;   s = 1.0f; }
    else if (y0 == -1)               { c0 = 0;     t = 0.0f; s = wy; }
    else if (y0 == H - 1)            { c0 = H - 2; t = 1.0f; s = 1.0f - wy; }
    else                             { c0 = 0;     t = 0.0f; s = 0.0f; }
}

__device__ __forceinline__ float tanh_fast(float x) {
    return 1.0f - 2.0f / (__expf(2.0f * x) + 1.0f);
}

// ---------------------------------------------------------------------------
// Kernel 0: transpose weights [c=24][ci=8][k=9] -> wT[k=9][ci=8][c=24]
// ---------------------------------------------------------------------------
__global__ void transpose_w_kernel(const float* __restrict__ w_oa, float* __restrict__ wT) {
    for (int i = threadIdx.x; i < 1728; i += 256) {
        const int k = i / 192;
        const int r = i - k * 192;
        const int ci = r / 24;
        const int c = r - ci * 24;
        wT[i] = w_oa[c * 72 + ci * 9 + k];
    }
}

// ---------------------------------------------------------------------------
// Kernel 1: per-pixel precompute — R13 structure; conv inner loop recast as
// 12x f32x2 packed FMA (v_pk_fma_f32, VOP3P) to halve conv VALU instruction
// count. Accumulators stay independent -> bit-identical numerics.
// Per tap j (8 B): u32{ (y0c*W+x0c) << 13 | aff13 }, u32{ half2(ty,tx) }
// aff13 includes the zero-pad scale sy*sx. affC = center weight * 8192.
// ---------------------------------------------------------------------------
__global__ __launch_bounds__(256) void precompute_kernel(
    const float* __restrict__ guidance,
    const float* __restrict__ confidence,
    const float* __restrict__ wT,
    const float* __restrict__ b_oa,
    const float* __restrict__ aff_scale,
    u32x4* __restrict__ PKa, u32x4* __restrict__ PKb,
    u32x4* __restrict__ PKc, u32x4* __restrict__ PKd,
    float* __restrict__ affC)
{
    const int p = blockIdx.x * 256 + threadIdx.x;
    const int b = p / HW;
    const int rem = p - b * HW;
    const int y = rem / WW;
    const int x = rem - y * WW;

    f32x2 acc2[12];
    {
        const f32x2* b2 = reinterpret_cast<const f32x2*>(b_oa);
        #pragma unroll
        for (int c2 = 0; c2 < 12; ++c2) acc2[c2] = b2[c2];   // uniform -> s_load
    }

    const float* gb = guidance + (size_t)b * 8 * HW;

    #pragma unroll 1
    for (int kidx = 0; kidx < 9; ++kidx) {
        const int yy = y + kidx / 3 - 1;
        const int xx = x + kidx % 3 - 1;
        const bool valid = ((unsigned)yy < (unsigned)HH) & ((unsigned)xx < (unsigned)WW);
        const int base = valid ? (yy * WW + xx) : 0;
        float g[8];
        #pragma unroll
        for (int ci = 0; ci < 8; ++ci) {
            float v = gb[ci * HW + base];
            g[ci] = valid ? v : 0.0f;
        }
        const float* wk = wT + kidx * 192;   // uniform address -> scalar loads
        #pragma unroll
        for (int ci = 0; ci < 8; ++ci) {
            const f32x2 gv2 = (f32x2){g[ci], g[ci]};
            const f32x2* wk2 = reinterpret_cast<const f32x2*>(wk + ci * 24);
            #pragma unroll
            for (int c2 = 0; c2 < 12; ++c2)
                acc2[c2] = __builtin_elementwise_fma(gv2, wk2[c2], acc2[c2]);
        }
    }

    float acc[24];
    #pragma unroll
    for (int c = 0; c < 24; ++c) acc[c] = acc2[c >> 1][c & 1];

    // --- affinity head ---
    const float inv_scale = 1.0f / (aff_scale[0] + 1e-8f);
    const float* cb = confidence + (size_t)b * HW;
    const float fy = (float)y, fx = (float)x;

    float affv[8];
    #pragma unroll
    for (int j = 0; j < 8; ++j) {
        const float oy = acc[j], ox = acc[8 + j];
        const float a = tanh_fast(acc[16 + j]) * inv_scale;
        const float ysj = fy + oy, xsj = fx + ox;
        const float y0f = floorf(ysj), x0f = floorf(xsj);
        const float wy = ysj - y0f, wx = xsj - x0f;
        const int y0 = (int)y0f, x0 = (int)x0f;
        const float v00 = ldz(cb, y0, x0),     v01 = ldz(cb, y0, x0 + 1);
        const float v10 = ldz(cb, y0 + 1, x0), v11 = ldz(cb, y0 + 1, x0 + 1);
        const float conf = v00 * (1.0f - wy) * (1.0f - wx) + v01 * (1.0f - wy) * wx
                         + v10 * wy * (1.0f - wx)          + v11 * wy * wx;
        affv[j] = a * conf;
    }

    float s = 1e-4f;
    #pragma unroll
    for (int j = 0; j < 8; ++j) s += fabsf(affv[j]);
    s = fmaxf(s, 1.0f);
    const float inv_s = 1.0f / s;
    float sum = 0.0f;
    #pragma unroll
    for (int j = 0; j < 8; ++j) { affv[j] *= inv_s; sum += affv[j]; }
    const float aref = 1.0f - sum;

    float m = aref;
    #pragma unroll
    for (int j = 0; j < 8; ++j) m = fmaxf(m, affv[j]);
    float e[8];
    float denom = 0.0f;
    #pragma unroll
    for (int j = 0; j < 8; ++j) { e[j] = __expf(affv[j] - m); denom += e[j]; }
    const float ec = __expf(aref - m);
    denom += ec;
    const float invden = 1.0f / denom;

    affC[p] = ec * invden * 8192.0f;   // pre-scaled center weight

    unsigned ba[8], tt[8];
    #pragma unroll
    for (int j = 0; j < 8; ++j) {
        const int t9 = (j < 4) ? j : j + 1;          // 9-tap index (skip center 4)
        const float khv = (float)(t9 / 3 - 1);
        const float kwv = (float)(t9 % 3 - 1);
        const float ys = (fy + khv) + acc[j];
        const float xs = (fx + kwv) + acc[8 + j];
        const float y0f = floorf(ys), x0f = floorf(xs);
        const float wy = ys - y0f, wx = xs - x0f;
        int y0c, x0c; float ty, tx, sy, sx;
        axis_map((int)y0f, wy, HH, y0c, ty, sy);
        axis_map((int)x0f, wx, WW, x0c, tx, sx);

        const float aeff = (e[j] * invden) * sy * sx;           // in [0,1)
        unsigned aq = __float2uint_rn(aeff * 8192.0f);
        aq = aq > 8191u ? 8191u : aq;
        ba[j] = ((unsigned)(y0c * WW + x0c) << 13) | aq;        // base19 | aff13
        __half2 h2 = __floats2half2_rn(ty, tx);                 // low = ty, high = tx
        tt[j] = __builtin_bit_cast(unsigned, h2);
    }
    PKa[p] = (u32x4){ba[0], tt[0], ba[1], tt[1]};
    PKb[p] = (u32x4){ba[2], tt[2], ba[3], tt[3]};
    PKc[p] = (u32x4){ba[4], tt[4], ba[5], tt[5]};
    PKd[p] = (u32x4){ba[6], tt[6], ba[7], tt[7]};
}

// ---------------------------------------------------------------------------
// Kernel 2: one propagation step — R14-proven best (23.1 us/iter).
// 4800 blocks, 1 px/thread, XCD-chunked swizzle, L3-cached param streams.
// ---------------------------------------------------------------------------
__global__ __launch_bounds__(256) void prop_kernel(
    const float* __restrict__ src,
    float* __restrict__ dst,
    const u32x4* __restrict__ PKa, const u32x4* __restrict__ PKb,
    const u32x4* __restrict__ PKc, const u32x4* __restrict__ PKd,
    const float* __restrict__ affC)
{
    const int bid = (blockIdx.x & 7) * (PROP_NBLK / 8) + (blockIdx.x >> 3);
    const int p = bid * 256 + threadIdx.x;
    const float* fb = src + (p / HW) * HW;   // uniform per block (HW % 256 == 0)

    const u32x4 qa = PKa[p];
    const u32x4 qb = PKb[p];
    const u32x4 qc = PKc[p];
    const u32x4 qd = PKd[p];
    const float ac = affC[p];

    float acc = ac * src[p];   // center tap

    auto tap = [&](unsigned bav, unsigned tw) {
        const float af = (float)(bav & 8191u);
        const float* g = fb + (bav >> 13);
        const float2 t2 = *reinterpret_cast<const float2*>(g);
        const float2 b2 = *reinterpret_cast<const float2*>(g + WW);
        const float2 t = __half22float2(__builtin_bit_cast(__half2, tw)); // (ty,tx)
        const float top = fmaf(t.y, t2.y - t2.x, t2.x);
        const float bot = fmaf(t.y, b2.y - b2.x, b2.x);
        acc = fmaf(af, fmaf(t.x, bot - top, top), acc);
    };
    tap(qa.x, qa.y); tap(qa.z, qa.w);
    tap(qb.x, qb.y); tap(qb.z, qb.w);
    tap(qc.x, qc.y); tap(qc.z, qc.w);
    tap(qd.x, qd.y); tap(qd.z, qd.w);

    dst[p] = acc * (1.0f / 8192.0f);
}

extern "C" void kernel_launch(void* const* d_in, const int* in_sizes, int n_in,
                              void* d_out, int out_size, void* d_ws, size_t ws_size,
                              hipStream_t stream) {
    const float* feat_init  = (const float*)d_in[0];
    const float* guidance   = (const float*)d_in[1];
    const float* confidence = (const float*)d_in[2];
    const float* w_oa       = (const float*)d_in[3];
    const float* b_oa       = (const float*)d_in[4];
    const float* aff_scale  = (const float*)d_in[5];
    float* out = (float*)d_out;
    float* ws  = (float*)d_ws;

    // ws layout (floats): PKa[4P] PKb[4P] PKc[4P] PKd[4P] | affC[P] | bufA[P]
    // wT (1728 floats) aliases bufA (dead before prop iter 0 writes it).
    const size_t need = (size_t)18 * PP * sizeof(float);
    if (ws_size < need) return;  // fail visibly rather than corrupt

    u32x4* PKa  = reinterpret_cast<u32x4*>(ws);
    u32x4* PKb  = reinterpret_cast<u32x4*>(ws + (size_t)4 * PP);
    u32x4* PKc  = reinterpret_cast<u32x4*>(ws + (size_t)8 * PP);
    u32x4* PKd  = reinterpret_cast<u32x4*>(ws + (size_t)12 * PP);
    float* affC = ws + (size_t)16 * PP;
    float* bufA = ws + (size_t)17 * PP;
    float* wT   = bufA;

    transpose_w_kernel<<<1, 256, 0, stream>>>(w_oa, wT);
    precompute_kernel<<<PP / 256, 256, 0, stream>>>(guidance, confidence, wT, b_oa,
                                                    aff_scale, PKa, PKb, PKc, PKd, affC);

    // ping-pong: even iters -> bufA, odd iters -> d_out (iter 17 -> d_out)
    const float* srcp = feat_init;
    for (int i = 0; i < 18; ++i) {
        float* dstp = (i & 1) ? out : bufA;
        prop_kernel<<<PROP_NBLK, 256, 0, stream>>>(srcp, dstp, PKa, PKb, PKc, PKd, affC);
        srcp = dstp;
    }
}